// Round 16
// baseline (84.855 us; speedup 1.0000x reference)
//
#include <hip/hip_runtime.h>
#include <hip/hip_bf16.h>
#include <math.h>

// FluxHead: B=4, T=4096, D_MODEL=1024, HEAD_DIM=128, STRIDE=4, Tk=1024, CAUSAL
// Exact-math simplifications:
//  - spectral gate adds a per-(b,q) scalar to logits -> softmax-invariant -> skipped
//  - reverse branch == unmasked forward attention, output read at mirror row
//  - pooling commutes with K/V projection -> pooled in GEMM epilogue (lane-local)
//  - log2e/SCALE folded into Wq -> softmax in exp2 units

#define T_ 4096
#define TK_ 1024

typedef __attribute__((ext_vector_type(8))) short bf16x8;
typedef __attribute__((ext_vector_type(4))) float f32x4;
typedef __attribute__((ext_vector_type(4))) short s16x4;
typedef __attribute__((address_space(1))) unsigned int gas_u32;
typedef __attribute__((address_space(3))) unsigned int las_u32;

__device__ inline short f2bf(float f) {
  unsigned u = __builtin_bit_cast(unsigned, f);
  u = (u + 0x7FFFu + ((u >> 16) & 1u)) >> 16;
  return (short)u;
}
__device__ inline f32x4 mfma16(bf16x8 a, bf16x8 b, f32x4 c) {
  return __builtin_amdgcn_mfma_f32_16x16x32_bf16(a, b, c, 0, 0, 0);
}
__device__ inline void gll16(const void* g, void* l) {
  __builtin_amdgcn_global_load_lds((gas_u32*)g, (las_u32*)l, 16, 0, 0);
}
#define VMCNT(n) asm volatile("s_waitcnt vmcnt(" #n ")" ::: "memory")

// ---- rope table: cos/sin[t][d], t<4096, d<64 ----
__global__ __launch_bounds__(256) void rope_kernel(float* __restrict__ cosT,
                                                   float* __restrict__ sinT) {
  int i = blockIdx.x * 256 + threadIdx.x;  // 262144
  int t = i >> 6, d = i & 63;
  float theta = powf(10000.f, -(float)d * (1.f / 64.f));
  float fr = (float)t * theta;
  cosT[i] = cosf(fr);
  sinT[i] = sinf(fr);
}

// ---- WT prep: [384][1024] bf16, PRE-SWIZZLED bytes within each 128B k-block:
// byte = ((k&63)*2) ^ ((n&7)<<4). Sections: [0..127]=Wq*scale, [128..255]=Wk,
// [256..383]=Wv. Q/K rows reordered so each wave's 64-col slice holds matched
// rope lo/hi pairs: row n: col = (n>>6)*32 + (n&31) + ((n>>5)&1)*64.
__global__ __launch_bounds__(256) void wtprep_kernel(const float* __restrict__ Wq,
                                                     const float* __restrict__ Wk,
                                                     const float* __restrict__ Wv,
                                                     char* __restrict__ WT) {
  int i = blockIdx.x * 256 + threadIdx.x;  // 384*1024
  int n = i >> 10, k = i & 1023;
  float v;
  if (n < 128) {
    int col = (n >> 6) * 32 + (n & 31) + ((n >> 5) & 1) * 64;
    v = Wq[(size_t)k * 128 + col] * 0.12751741656f;  // log2(e)/sqrt(128)
  } else if (n < 256) {
    int nk = n - 128;
    int col = (nk >> 6) * 32 + (nk & 31) + ((nk >> 5) & 1) * 64;
    v = Wk[(size_t)k * 128 + col];
  } else {
    v = Wv[(size_t)k * 128 + (n - 256)];
  }
  size_t off = (size_t)n * 2048 + (size_t)(k >> 6) * 128 + (((k & 63) * 2) ^ ((n & 7) << 4));
  *(short*)(WT + off) = f2bf(v);
}

// ---- projection GEMM v3: 2-wave blocks, 64x64 wave tile (4x4 acc), BM=64 BN=128.
// Grid 768 (trio-XCD-packed) -> 3 blocks/CU at 48 KB LDS, 6 waves/CU.
// LDS instrs/CU-iter: 120 (was 168) -> attacks the measured LDS-port wall.
// Sync: r10/r15-proven dbuf + one __syncthreads per K-step (no counted vmcnt).
__global__ __launch_bounds__(128, 2) void gemm_fused(const float* __restrict__ x,
                                                     const char* __restrict__ WT,
                                                     const float* __restrict__ cosT,
                                                     const float* __restrict__ sinT,
                                                     short* __restrict__ Qb,
                                                     char* __restrict__ Kswz,
                                                     char* __restrict__ Vswz) {
  __shared__ __align__(16) char Al[2][8192];    // 64 rows x 64 k bf16, swizzled
  __shared__ __align__(16) char Bl[2][16384];   // 128 rows x 64 k bf16, pre-swz copy
  const int tid = threadIdx.x;
  const int w = tid >> 6, g = (tid >> 4) & 3, c = tid & 15;
  const int wc = w;                              // wave = N-half; all 64 M rows
  const int swc = (c & 7) << 4;
  const int x8 = blockIdx.x & 7, jj0 = blockIdx.x >> 3;  // jj0: 0..95
  const int nb = jj0 % 3, tl = jj0 / 3;                  // 32 trios per XCD
  const int mt = x8 * 32 + tl;
  const int m0 = mt * 64;
  const char* WTB = WT + (size_t)nb * 128 * 2048;
  // A staging role: 2 threads/row, 128 B f32 each (r12-proven)
  const int arow = tid >> 1, apart = tid & 1;
  const int sws = (arow & 7) << 4;
  const float* xsrc = x + (size_t)(m0 + arow) * 1024 + apart * 32;

  f32x4 acc[4][4];
#pragma unroll
  for (int mf = 0; mf < 4; mf++)
#pragma unroll
    for (int n = 0; n < 4; n++) acc[mf][n] = (f32x4){0.f, 0.f, 0.f, 0.f};

  float4 areg[8];
  auto ALOAD = [&](int ki) {
#pragma unroll
    for (int t = 0; t < 8; t++) areg[t] = *(const float4*)(xsrc + (size_t)ki * 64 + t * 4);
  };
  auto AWRITE = [&](int buf) {
#pragma unroll
    for (int i2 = 0; i2 < 4; i2++) {
      bf16x8 v = {f2bf(areg[2 * i2].x),     f2bf(areg[2 * i2].y),
                  f2bf(areg[2 * i2].z),     f2bf(areg[2 * i2].w),
                  f2bf(areg[2 * i2 + 1].x), f2bf(areg[2 * i2 + 1].y),
                  f2bf(areg[2 * i2 + 1].z), f2bf(areg[2 * i2 + 1].w)};
      *(bf16x8*)(Al[buf] + arow * 128 + ((apart * 64 + i2 * 16) ^ sws)) = v;
    }
  };
  auto BSTAGE = [&](int ki, int buf) {
#pragma unroll
    for (int i2 = 0; i2 < 8; i2++) {
      int j = tid + 128 * i2;
      gll16(WTB + (size_t)(j >> 3) * 2048 + ki * 128 + (j & 7) * 16, Bl[buf] + j * 16);
    }
  };
  auto COMPUTE = [&](int buf) {
#pragma unroll
    for (int kc = 0; kc < 2; kc++) {
      bf16x8 af[4], bfr[4];
#pragma unroll
      for (int mf = 0; mf < 4; mf++)
        af[mf] = *(const bf16x8*)(Al[buf] + (mf * 16 + c) * 128 + ((kc * 64 + 16 * g) ^ swc));
#pragma unroll
      for (int n0 = 0; n0 < 4; n0++) {
        int row = wc * 64 + n0 * 16 + c;
        bfr[n0] = *(const bf16x8*)(Bl[buf] + row * 128 + ((kc * 64 + 16 * g) ^ ((row & 7) << 4)));
      }
#pragma unroll
      for (int mf = 0; mf < 4; mf++)
#pragma unroll
        for (int n0 = 0; n0 < 4; n0++) acc[mf][n0] = mfma16(af[mf], bfr[n0], acc[mf][n0]);
    }
  };

  // prologue: tile 0 into buf0; x(1) into regs  (r10-proven loop shape)
  ALOAD(0);
  AWRITE(0);
  BSTAGE(0, 0);
  ALOAD(1);
  __syncthreads();
#pragma unroll 1
  for (int ki = 0; ki < 16; ki++) {
    const int cur = ki & 1;
    if (ki + 1 < 16) {
      AWRITE(cur ^ 1);                    // x(ki+1) regs -> other A buffer
      BSTAGE(ki + 1, cur ^ 1);            // W(ki+1) -> other B buffer
      ALOAD(ki + 2 < 16 ? ki + 2 : 15);   // x(ki+2) -> regs (lands during COMPUTE)
    }
    COMPUTE(cur);
    __syncthreads();
  }

  // ---- epilogue: acc[mf][n0][r] = C[m0 + mf*16 + 4g + r][wc*64 + n0*16 + c]
  if (nb == 0) {
#pragma unroll
    for (int mf = 0; mf < 4; mf++)
#pragma unroll
      for (int r = 0; r < 4; r++) {
        int mm = m0 + mf * 16 + 4 * g + r;
        int t = mm & 4095;
#pragma unroll
        for (int n0 = 0; n0 < 2; n0++) {
          int d = wc * 32 + n0 * 16 + c;
          float co = cosT[t * 64 + d], si = sinT[t * 64 + d];
          float lo = acc[mf][n0][r], hi = acc[mf][n0 + 2][r];
          Qb[(size_t)mm * 128 + d] = f2bf(lo * co - hi * si);
          Qb[(size_t)mm * 128 + d + 64] = f2bf(hi * co + lo * si);
        }
      }
  } else if (nb == 1) {
#pragma unroll
    for (int mf = 0; mf < 4; mf++) {
      int kp = ((m0 + mf * 16) >> 2) + g;
      int kpos = kp & 1023;
      int ksw = (kp & 7) << 4;
      char* kb2 = Kswz + (size_t)kp * 256;
#pragma unroll
      for (int n0 = 0; n0 < 2; n0++) {
        int d = wc * 32 + n0 * 16 + c;
        float lo = 0.25f * (acc[mf][n0][0] + acc[mf][n0][1] + acc[mf][n0][2] + acc[mf][n0][3]);
        float hi = 0.25f * (acc[mf][n0 + 2][0] + acc[mf][n0 + 2][1] + acc[mf][n0 + 2][2] + acc[mf][n0 + 2][3]);
        float co = cosT[kpos * 64 + d], si = sinT[kpos * 64 + d];
        *(short*)(kb2 + ((d * 2) ^ ksw)) = f2bf(lo * co - hi * si);
        *(short*)(kb2 + (((d + 64) * 2) ^ ksw)) = f2bf(hi * co + lo * si);
      }
    }
  } else {
    // V: pool over r, store [b][subtile32][64 r][144B]: byte = r*144 + h*64 + kk*2
#pragma unroll
    for (int mf = 0; mf < 4; mf++) {
      int kp = ((m0 + mf * 16) >> 2) + g;
      int kpos = kp & 1023, bb = kp >> 10;
#pragma unroll
      for (int n0 = 0; n0 < 4; n0++) {
        int r = n0 * 16 + c;  // d = wc*64 + r, h = wc
        float vp = 0.25f * (acc[mf][n0][0] + acc[mf][n0][1] + acc[mf][n0][2] + acc[mf][n0][3]);
        size_t off = (size_t)(bb * 32 + (kpos >> 5)) * 9216 + r * 144 + wc * 64 +
                     (kpos & 31) * 2;
        *(short*)(Vswz + off) = f2bf(vp);
      }
    }
  }
}

// ---- fused two-branch flash attention, mirror-paired block, KVBLK=64 ----
// [byte-identical to round-15: r11 structure + s_setprio around MFMA clusters]
__global__ __launch_bounds__(256, 2) void attn_kernel(const short* __restrict__ Qb,
                                                      const char* __restrict__ Kswz,
                                                      const char* __restrict__ Vswz,
                                                      const float* __restrict__ alphap,
                                                      float* __restrict__ out) {
  __shared__ __align__(16) char lds[32768 + 36864 + 4 * 2304];  // K + V + P = 78848
  char* Kl = lds;            // 2 bufs x [64 keys x 256B] (pre-swz rows)
  char* Vl = lds + 32768;    // 2 bufs x [2 subtiles x [64 r][144B]]
  const int tid = threadIdx.x;
  const int w = tid >> 6, g = (tid >> 4) & 3, c = tid & 15;
  char* Pl = lds + 69632 + w * 2304;  // 16 q-rows x 144B
  const int blk = blockIdx.x;
  const int b = blk >> 7, qc = blk & 127;
  const int q0b = qc * 32;
  const bool isC = (w < 2);
  const int qbase = isC ? (q0b + w * 16) : (4064 - q0b + (w - 2) * 16);
  const int myq = qbase + c;
  const int tile_b = qbase >> 8;  // boundary 64-key tile for this wave
  const int swc = (c & 7) << 4;

  bf16x8 qf[4];
  {
    const short* qr = Qb + ((size_t)b * T_ + myq) * 128;
#pragma unroll
    for (int kc = 0; kc < 4; kc++) qf[kc] = *(const bf16x8*)(qr + kc * 32 + 8 * g);
  }
  f32x4 acc[8];
#pragma unroll
  for (int n = 0; n < 8; n++) acc[n] = (f32x4){0.f, 0.f, 0.f, 0.f};
  float m = -1e30f, l = 0.f;

  const char* kbB = Kswz + (size_t)b * 262144;
  const char* vbB = Vswz + (size_t)b * 294912;

  auto STG = [&](int tg, char* kd, char* vd) {
    const char* kb = kbB + (size_t)tg * 16384;
    const char* vb = vbB + (size_t)tg * 18432;
#pragma unroll
    for (int jj = 0; jj < 4; jj++) gll16(kb + jj * 4096 + tid * 16, kd + jj * 4096 + tid * 16);
#pragma unroll
    for (int jj = 0; jj < 4; jj++) gll16(vb + jj * 4096 + tid * 16, vd + jj * 4096 + tid * 16);
    if (tid < 128) gll16(vb + 16384 + tid * 16, vd + 16384 + tid * 16);  // 2KB tail
  };

  STG(0, Kl, Vl);

#pragma unroll 1
  for (int tg = 0; tg < 16; tg++) {
    const int kcur = (tg & 1) * 16384;
    const int vcur = (tg & 1) * 18432;
    if (tg < 15) {
      STG(tg + 1, Kl + (16384 - kcur), Vl + (18432 - vcur));
      if (w < 2) { VMCNT(9); } else { VMCNT(8); }  // drain prev tile; keep newest
    } else {
      VMCNT(0);
    }
    __builtin_amdgcn_s_barrier();

    if (!isC || tg <= tile_b) {
      // QK^T swapped: s[n][r] = S[key = tg*64 + 16n + 4g + r][q = myq]
      f32x4 s[4];
#pragma unroll
      for (int n = 0; n < 4; n++) s[n] = (f32x4){0.f, 0.f, 0.f, 0.f};
      __builtin_amdgcn_s_setprio(1);
#pragma unroll
      for (int kc = 0; kc < 4; kc++) {
#pragma unroll
        for (int n = 0; n < 4; n++) {
          bf16x8 kf = *(const bf16x8*)(Kl + kcur + (16 * n + c) * 256 + ((kc * 64 + 16 * g) ^ swc));
          s[n] = mfma16(kf, qf[kc], s[n]);
        }
      }
      __builtin_amdgcn_s_setprio(0);
      if (isC && tg == tile_b) {  // boundary mask
        int klim = (myq >> 2) - tg * 64;
#pragma unroll
        for (int n = 0; n < 4; n++)
#pragma unroll
          for (int r = 0; r < 4; r++)
            if (16 * n + 4 * g + r > klim) s[n][r] = -3.0e38f;
      }
      float tm = fmaxf(fmaxf(fmaxf(s[0][0], s[0][1]), fmaxf(s[0][2], s[0][3])),
                       fmaxf(fmaxf(s[1][0], s[1][1]), fmaxf(s[1][2], s[1][3])));
      tm = fmaxf(tm, fmaxf(fmaxf(fmaxf(s[2][0], s[2][1]), fmaxf(s[2][2], s[2][3])),
                           fmaxf(fmaxf(s[3][0], s[3][1]), fmaxf(s[3][2], s[3][3]))));
      tm = fmaxf(tm, __shfl_xor(tm, 16));
      tm = fmaxf(tm, __shfl_xor(tm, 32));
      if (__any(tm > m + 8.f)) {  // defer-max
        float mn = fmaxf(m, tm);
        float sc = __builtin_amdgcn_exp2f(m - mn);
        m = mn;
        l *= sc;
        float s0 = __shfl(sc, 4 * g), s1 = __shfl(sc, 4 * g + 1);
        float s2 = __shfl(sc, 4 * g + 2), s3 = __shfl(sc, 4 * g + 3);
        f32x4 scv = {s0, s1, s2, s3};
#pragma unroll
        for (int n0 = 0; n0 < 8; n0++) acc[n0] *= scv;
      }
      float rsum = 0.f;
#pragma unroll
      for (int n = 0; n < 4; n++) {
        float p0 = __builtin_amdgcn_exp2f(s[n][0] - m);
        float p1 = __builtin_amdgcn_exp2f(s[n][1] - m);
        float p2 = __builtin_amdgcn_exp2f(s[n][2] - m);
        float p3 = __builtin_amdgcn_exp2f(s[n][3] - m);
        rsum += (p0 + p1) + (p2 + p3);
        s16x4 pk = {f2bf(p0), f2bf(p1), f2bf(p2), f2bf(p3)};
        *(s16x4*)(Pl + c * 144 + 32 * n + 8 * g) = pk;  // keys 16n+4g..+3
      }
      rsum += __shfl_xor(rsum, 16);
      rsum += __shfl_xor(rsum, 32);
      l += rsum;
#pragma unroll
      for (int kc = 0; kc < 2; kc++) {
        bf16x8 pf = *(const bf16x8*)(Pl + c * 144 + 64 * kc + 16 * g);  // keys 32kc+8g..+7
        __builtin_amdgcn_s_setprio(1);
#pragma unroll
        for (int n0 = 0; n0 < 8; n0++) {
          bf16x8 v0 = *(const bf16x8*)(Vl + vcur + kc * 9216 +
                                       ((n0 & 3) * 16 + c) * 144 + (n0 >> 2) * 64 + 16 * g);
          acc[n0] = mfma16(pf, v0, acc[n0]);
        }
        __builtin_amdgcn_s_setprio(0);
      }
    }
    __builtin_amdgcn_s_barrier();
  }

  // epilogue: per-output-row 1/l, exchange U through LDS, combine, write
  float lr0 = __shfl(l, 4 * g), lr1 = __shfl(l, 4 * g + 1);
  float lr2 = __shfl(l, 4 * g + 2), lr3 = __shfl(l, 4 * g + 3);
  f32x4 linv = {1.f / lr0, 1.f / lr1, 1.f / lr2, 1.f / lr3};
  float* Ul = (float*)lds;  // [32][132] overlay = 16.9 KB (all K/V reads done)
  if (!isC) {
#pragma unroll
    for (int n0 = 0; n0 < 8; n0++)
#pragma unroll
      for (int r = 0; r < 4; r++) {
        int urow = 31 - (16 * (w - 2) + 4 * g + r);
        Ul[urow * 132 + n0 * 16 + c] = acc[n0][r] * linv[r];
      }
  }
  __syncthreads();
  if (isC) {
    float alpha = 1.f / (1.f + expf(-alphap[0]));
    float oma = 1.f - alpha;
#pragma unroll
    for (int n0 = 0; n0 < 8; n0++)
#pragma unroll
      for (int r = 0; r < 4; r++) {
        int j = 16 * w + 4 * g + r;
        float uvv = Ul[j * 132 + n0 * 16 + c];
        out[((size_t)b * T_ + q0b + j) * 128 + n0 * 16 + c] =
            alpha * acc[n0][r] * linv[r] + oma * uvv;
      }
  }
}

extern "C" void kernel_launch(void* const* d_in, const int* in_sizes, int n_in,
                              void* d_out, int out_size, void* d_ws, size_t ws_size,
                              hipStream_t stream) {
  const float* x = (const float*)d_in[0];
  const float* Wq = (const float*)d_in[1];
  const float* Wk = (const float*)d_in[2];
  const float* Wv = (const float*)d_in[3];
  const float* falpha = (const float*)d_in[9];
  char* ws = (char*)d_ws;
  float* cosT = (float*)(ws);                  // 1 MB
  float* sinT = (float*)(ws + 1048576);        // 1 MB
  char* WT = ws + 2097152;                     // 768 KB  [384][1024] bf16, pre-swizzled
  short* Qb = (short*)(ws + 2883584);          // 4 MB    roped+scaled Q bf16
  char* Kswz = ws + 7077888;                   // 1 MB    roped pooled K bf16, swizzled
  char* Vswz = ws + 8126464;                   // 1.18 MB pooled V, [b][subtile32][64r][144B]

  rope_kernel<<<1024, 256, 0, stream>>>(cosT, sinT);
  wtprep_kernel<<<1536, 256, 0, stream>>>(Wq, Wk, Wv, WT);
  gemm_fused<<<768, 128, 0, stream>>>(x, WT, cosT, sinT, Qb, Kswz, Vswz);
  attn_kernel<<<512, 256, 0, stream>>>(Qb, Kswz, Vswz, falpha, (float*)d_out);
}

// Round 17
// 79.081 us; speedup vs baseline: 1.0730x; 1.0730x over previous
//
#include <hip/hip_runtime.h>
#include <hip/hip_bf16.h>
#include <math.h>

// FluxHead: B=4, T=4096, D_MODEL=1024, HEAD_DIM=128, STRIDE=4, Tk=1024, CAUSAL
// Exact-math simplifications:
//  - spectral gate adds a per-(b,q) scalar to logits -> softmax-invariant -> skipped
//  - reverse branch == unmasked forward attention, output read at mirror row
//  - pooling commutes with K/V projection -> pooled in GEMM epilogue (lane-local)
//  - log2e/SCALE folded into Wq -> softmax in exp2 units

#define T_ 4096
#define TK_ 1024

typedef __attribute__((ext_vector_type(8))) short bf16x8;
typedef __attribute__((ext_vector_type(4))) float f32x4;
typedef __attribute__((ext_vector_type(4))) short s16x4;
typedef __attribute__((ext_vector_type(4))) unsigned int u32x4;
typedef __attribute__((address_space(1))) unsigned int gas_u32;
typedef __attribute__((address_space(3))) unsigned int las_u32;

__device__ inline short f2bf(float f) {
  unsigned u = __builtin_bit_cast(unsigned, f);
  u = (u + 0x7FFFu + ((u >> 16) & 1u)) >> 16;
  return (short)u;
}
__device__ inline unsigned pkbf(float a, float b) {
  unsigned r;
  asm("v_cvt_pk_bf16_f32 %0, %1, %2" : "=v"(r) : "v"(a), "v"(b));
  return r;
}
__device__ inline f32x4 mfma16(bf16x8 a, bf16x8 b, f32x4 c) {
  return __builtin_amdgcn_mfma_f32_16x16x32_bf16(a, b, c, 0, 0, 0);
}
__device__ inline void gll16(const void* g, void* l) {
  __builtin_amdgcn_global_load_lds((gas_u32*)g, (las_u32*)l, 16, 0, 0);
}
#define VMCNT(n) asm volatile("s_waitcnt vmcnt(" #n ")" ::: "memory")

// ---- prep: rope table (blocks 0..1023) + WT pre-swizzle (blocks 1024..2559) ----
__global__ __launch_bounds__(256) void prep_kernel(const float* __restrict__ Wq,
                                                   const float* __restrict__ Wk,
                                                   const float* __restrict__ Wv,
                                                   float* __restrict__ cosT,
                                                   float* __restrict__ sinT,
                                                   char* __restrict__ WT) {
  if (blockIdx.x < 1024) {
    int i = blockIdx.x * 256 + threadIdx.x;  // 262144
    int t = i >> 6, d = i & 63;
    float theta = powf(10000.f, -(float)d * (1.f / 64.f));
    float fr = (float)t * theta;
    cosT[i] = cosf(fr);
    sinT[i] = sinf(fr);
  } else {
    int i = (blockIdx.x - 1024) * 256 + threadIdx.x;  // 384*1024
    int n = i >> 10, k = i & 1023;
    float v;
    if (n < 128) {
      int col = (n >> 6) * 32 + (n & 31) + ((n >> 5) & 1) * 64;
      v = Wq[(size_t)k * 128 + col] * 0.12751741656f;  // log2(e)/sqrt(128)
    } else if (n < 256) {
      int nk = n - 128;
      int col = (nk >> 6) * 32 + (nk & 31) + ((nk >> 5) & 1) * 64;
      v = Wk[(size_t)k * 128 + col];
    } else {
      v = Wv[(size_t)k * 128 + (n - 256)];
    }
    size_t off = (size_t)n * 2048 + (size_t)(k >> 6) * 128 + (((k & 63) * 2) ^ ((n & 7) << 4));
    *(short*)(WT + off) = f2bf(v);
  }
}

// ---- projection GEMM v4: BOTH operands via global_load_lds (homogeneous queue,
// r5-proven counted-vmcnt ping-pong). A staged as RAW F32 from x (pre-swizzled
// source addr, linear LDS dst); cvt->bf16 at fragment build via v_cvt_pk_bf16_f32.
// grid 768 = 8 XCD x (32 M-tiles x 3 N-blocks), trio-XCD-packed. LDS 64 KB.
__global__ __launch_bounds__(256, 2) void gemm_fused(const float* __restrict__ x,
                                                     const char* __restrict__ WT,
                                                     const float* __restrict__ cosT,
                                                     const float* __restrict__ sinT,
                                                     short* __restrict__ Qb,
                                                     char* __restrict__ Kswz,
                                                     char* __restrict__ Vswz) {
  __shared__ __align__(16) char Af[2][16384];   // 64 rows x 256B f32, src-swizzled
  __shared__ __align__(16) char Bf[2][16384];   // 128 rows x 128B bf16, pre-swz
  const int tid = threadIdx.x;
  const int w = tid >> 6, g = (tid >> 4) & 3, c = tid & 15;
  const int wr = w >> 1, wc = w & 1;
  const int swc = (c & 7) << 4;
  const int x8 = blockIdx.x & 7, jj0 = blockIdx.x >> 3;  // jj0: 0..95
  const int nb = jj0 % 3, tl = jj0 / 3;                  // 32 trios per XCD
  const int mt = x8 * 32 + tl;
  const int m0 = mt * 64;
  const char* WTB = WT + (size_t)nb * 128 * 2048;

  f32x4 acc[2][4];
#pragma unroll
  for (int mf = 0; mf < 2; mf++)
#pragma unroll
    for (int n = 0; n < 4; n++) acc[mf][n] = (f32x4){0.f, 0.f, 0.f, 0.f};

  // A staging: 1024 chunks of 16B; thread handles chunks tid + 256*i2.
  // LDS slot s of row r holds global slot s^(r&7)  (16B slots, 16 per row).
  auto STAGE = [&](int ki, int buf) {
#pragma unroll
    for (int i2 = 0; i2 < 4; i2++) {
      int ch = tid + 256 * i2;
      int row = ch >> 4, s = ch & 15;
      int gslot = s ^ (row & 7);
      gll16(x + (size_t)(m0 + row) * 1024 + ki * 64 + gslot * 4, Af[buf] + ch * 16);
    }
#pragma unroll
    for (int i2 = 0; i2 < 4; i2++) {
      int j = tid + 256 * i2;
      gll16(WTB + (size_t)(j >> 3) * 2048 + ki * 128 + (j & 7) * 16, Bf[buf] + j * 16);
    }
  };
  auto COMPUTE = [&](int buf) {
#pragma unroll
    for (int kc = 0; kc < 2; kc++) {
      bf16x8 af[2], bfr[4];
#pragma unroll
      for (int mf = 0; mf < 2; mf++) {
        int arow = wr * 32 + mf * 16 + c;
        int as = (arow & 7) << 4;
        float4 lo = *(const float4*)(Af[buf] + arow * 256 + ((kc * 128 + 32 * g) ^ as));
        float4 hi = *(const float4*)(Af[buf] + arow * 256 + ((kc * 128 + 32 * g + 16) ^ as));
        u32x4 u = {pkbf(lo.x, lo.y), pkbf(lo.z, lo.w), pkbf(hi.x, hi.y), pkbf(hi.z, hi.w)};
        af[mf] = __builtin_bit_cast(bf16x8, u);
      }
#pragma unroll
      for (int n0 = 0; n0 < 4; n0++) {
        int row = wc * 64 + n0 * 16 + c;
        bfr[n0] = *(const bf16x8*)(Bf[buf] + row * 128 + ((kc * 64 + 16 * g) ^ ((row & 7) << 4)));
      }
#pragma unroll
      for (int mf = 0; mf < 2; mf++)
#pragma unroll
        for (int n0 = 0; n0 < 4; n0++) acc[mf][n0] = mfma16(af[mf], bfr[n0], acc[mf][n0]);
    }
  };

  STAGE(0, 0);  // 8 gll16 in flight
#pragma unroll 1
  for (int ki = 0; ki < 16; ki += 2) {
    STAGE(ki + 1, 1);       // queue: tile(ki) 8 older + tile(ki+1) 8 newer
    VMCNT(8);               // drain tile(ki); keep tile(ki+1) in flight
    __builtin_amdgcn_s_barrier();
    COMPUTE(0);
    __builtin_amdgcn_s_barrier();
    if (ki + 2 < 16) {
      STAGE(ki + 2, 0);     // queue: tile(ki+1) + tile(ki+2)
      VMCNT(8);             // drain tile(ki+1); keep tile(ki+2)
    } else {
      VMCNT(0);
    }
    __builtin_amdgcn_s_barrier();
    COMPUTE(1);
    __builtin_amdgcn_s_barrier();
  }

  // ---- epilogue: acc[mf][n0][r] = C[m0 + wr*32 + mf*16 + 4g + r][wc*64 + n0*16 + c]
  if (nb == 0) {
#pragma unroll
    for (int mf = 0; mf < 2; mf++)
#pragma unroll
      for (int r = 0; r < 4; r++) {
        int mm = m0 + wr * 32 + mf * 16 + 4 * g + r;
        int t = mm & 4095;
#pragma unroll
        for (int n0 = 0; n0 < 2; n0++) {
          int d = wc * 32 + n0 * 16 + c;
          float co = cosT[t * 64 + d], si = sinT[t * 64 + d];
          float lo = acc[mf][n0][r], hi = acc[mf][n0 + 2][r];
          Qb[(size_t)mm * 128 + d] = f2bf(lo * co - hi * si);
          Qb[(size_t)mm * 128 + d + 64] = f2bf(hi * co + lo * si);
        }
      }
  } else if (nb == 1) {
#pragma unroll
    for (int mf = 0; mf < 2; mf++) {
      int kp = ((m0 + wr * 32 + mf * 16) >> 2) + g;
      int kpos = kp & 1023;
      int ksw = (kp & 7) << 4;
      char* kb2 = Kswz + (size_t)kp * 256;
#pragma unroll
      for (int n0 = 0; n0 < 2; n0++) {
        int d = wc * 32 + n0 * 16 + c;
        float lo = 0.25f * (acc[mf][n0][0] + acc[mf][n0][1] + acc[mf][n0][2] + acc[mf][n0][3]);
        float hi = 0.25f * (acc[mf][n0 + 2][0] + acc[mf][n0 + 2][1] + acc[mf][n0 + 2][2] + acc[mf][n0 + 2][3]);
        float co = cosT[kpos * 64 + d], si = sinT[kpos * 64 + d];
        *(short*)(kb2 + ((d * 2) ^ ksw)) = f2bf(lo * co - hi * si);
        *(short*)(kb2 + (((d + 64) * 2) ^ ksw)) = f2bf(hi * co + lo * si);
      }
    }
  } else {
    // V: pool over r, store [b][subtile32][64 r][144B]: byte = r*144 + h*64 + kk*2
#pragma unroll
    for (int mf = 0; mf < 2; mf++) {
      int kp = ((m0 + wr * 32 + mf * 16) >> 2) + g;
      int kpos = kp & 1023, bb = kp >> 10;
#pragma unroll
      for (int n0 = 0; n0 < 4; n0++) {
        int r = n0 * 16 + c;  // d = wc*64 + r, h = wc
        float vp = 0.25f * (acc[mf][n0][0] + acc[mf][n0][1] + acc[mf][n0][2] + acc[mf][n0][3]);
        size_t off = (size_t)(bb * 32 + (kpos >> 5)) * 9216 + r * 144 + wc * 64 +
                     (kpos & 31) * 2;
        *(short*)(Vswz + off) = f2bf(vp);
      }
    }
  }
}

// ---- fused two-branch flash attention, mirror-paired block, KVBLK=64 ----
// [byte-identical to round-15: r11 structure + s_setprio around MFMA clusters]
__global__ __launch_bounds__(256, 2) void attn_kernel(const short* __restrict__ Qb,
                                                      const char* __restrict__ Kswz,
                                                      const char* __restrict__ Vswz,
                                                      const float* __restrict__ alphap,
                                                      float* __restrict__ out) {
  __shared__ __align__(16) char lds[32768 + 36864 + 4 * 2304];  // K + V + P = 78848
  char* Kl = lds;            // 2 bufs x [64 keys x 256B] (pre-swz rows)
  char* Vl = lds + 32768;    // 2 bufs x [2 subtiles x [64 r][144B]]
  const int tid = threadIdx.x;
  const int w = tid >> 6, g = (tid >> 4) & 3, c = tid & 15;
  char* Pl = lds + 69632 + w * 2304;  // 16 q-rows x 144B
  const int blk = blockIdx.x;
  const int b = blk >> 7, qc = blk & 127;
  const int q0b = qc * 32;
  const bool isC = (w < 2);
  const int qbase = isC ? (q0b + w * 16) : (4064 - q0b + (w - 2) * 16);
  const int myq = qbase + c;
  const int tile_b = qbase >> 8;  // boundary 64-key tile for this wave
  const int swc = (c & 7) << 4;

  bf16x8 qf[4];
  {
    const short* qr = Qb + ((size_t)b * T_ + myq) * 128;
#pragma unroll
    for (int kc = 0; kc < 4; kc++) qf[kc] = *(const bf16x8*)(qr + kc * 32 + 8 * g);
  }
  f32x4 acc[8];
#pragma unroll
  for (int n = 0; n < 8; n++) acc[n] = (f32x4){0.f, 0.f, 0.f, 0.f};
  float m = -1e30f, l = 0.f;

  const char* kbB = Kswz + (size_t)b * 262144;
  const char* vbB = Vswz + (size_t)b * 294912;

  auto STG = [&](int tg, char* kd, char* vd) {
    const char* kb = kbB + (size_t)tg * 16384;
    const char* vb = vbB + (size_t)tg * 18432;
#pragma unroll
    for (int jj = 0; jj < 4; jj++) gll16(kb + jj * 4096 + tid * 16, kd + jj * 4096 + tid * 16);
#pragma unroll
    for (int jj = 0; jj < 4; jj++) gll16(vb + jj * 4096 + tid * 16, vd + jj * 4096 + tid * 16);
    if (tid < 128) gll16(vb + 16384 + tid * 16, vd + 16384 + tid * 16);  // 2KB tail
  };

  STG(0, Kl, Vl);

#pragma unroll 1
  for (int tg = 0; tg < 16; tg++) {
    const int kcur = (tg & 1) * 16384;
    const int vcur = (tg & 1) * 18432;
    if (tg < 15) {
      STG(tg + 1, Kl + (16384 - kcur), Vl + (18432 - vcur));
      if (w < 2) { VMCNT(9); } else { VMCNT(8); }  // drain prev tile; keep newest
    } else {
      VMCNT(0);
    }
    __builtin_amdgcn_s_barrier();

    if (!isC || tg <= tile_b) {
      // QK^T swapped: s[n][r] = S[key = tg*64 + 16n + 4g + r][q = myq]
      f32x4 s[4];
#pragma unroll
      for (int n = 0; n < 4; n++) s[n] = (f32x4){0.f, 0.f, 0.f, 0.f};
      __builtin_amdgcn_s_setprio(1);
#pragma unroll
      for (int kc = 0; kc < 4; kc++) {
#pragma unroll
        for (int n = 0; n < 4; n++) {
          bf16x8 kf = *(const bf16x8*)(Kl + kcur + (16 * n + c) * 256 + ((kc * 64 + 16 * g) ^ swc));
          s[n] = mfma16(kf, qf[kc], s[n]);
        }
      }
      __builtin_amdgcn_s_setprio(0);
      if (isC && tg == tile_b) {  // boundary mask
        int klim = (myq >> 2) - tg * 64;
#pragma unroll
        for (int n = 0; n < 4; n++)
#pragma unroll
          for (int r = 0; r < 4; r++)
            if (16 * n + 4 * g + r > klim) s[n][r] = -3.0e38f;
      }
      float tm = fmaxf(fmaxf(fmaxf(s[0][0], s[0][1]), fmaxf(s[0][2], s[0][3])),
                       fmaxf(fmaxf(s[1][0], s[1][1]), fmaxf(s[1][2], s[1][3])));
      tm = fmaxf(tm, fmaxf(fmaxf(fmaxf(s[2][0], s[2][1]), fmaxf(s[2][2], s[2][3])),
                           fmaxf(fmaxf(s[3][0], s[3][1]), fmaxf(s[3][2], s[3][3]))));
      tm = fmaxf(tm, __shfl_xor(tm, 16));
      tm = fmaxf(tm, __shfl_xor(tm, 32));
      if (__any(tm > m + 8.f)) {  // defer-max
        float mn = fmaxf(m, tm);
        float sc = __builtin_amdgcn_exp2f(m - mn);
        m = mn;
        l *= sc;
        float s0 = __shfl(sc, 4 * g), s1 = __shfl(sc, 4 * g + 1);
        float s2 = __shfl(sc, 4 * g + 2), s3 = __shfl(sc, 4 * g + 3);
        f32x4 scv = {s0, s1, s2, s3};
#pragma unroll
        for (int n0 = 0; n0 < 8; n0++) acc[n0] *= scv;
      }
      float rsum = 0.f;
#pragma unroll
      for (int n = 0; n < 4; n++) {
        float p0 = __builtin_amdgcn_exp2f(s[n][0] - m);
        float p1 = __builtin_amdgcn_exp2f(s[n][1] - m);
        float p2 = __builtin_amdgcn_exp2f(s[n][2] - m);
        float p3 = __builtin_amdgcn_exp2f(s[n][3] - m);
        rsum += (p0 + p1) + (p2 + p3);
        s16x4 pk = {f2bf(p0), f2bf(p1), f2bf(p2), f2bf(p3)};
        *(s16x4*)(Pl + c * 144 + 32 * n + 8 * g) = pk;  // keys 16n+4g..+3
      }
      rsum += __shfl_xor(rsum, 16);
      rsum += __shfl_xor(rsum, 32);
      l += rsum;
#pragma unroll
      for (int kc = 0; kc < 2; kc++) {
        bf16x8 pf = *(const bf16x8*)(Pl + c * 144 + 64 * kc + 16 * g);  // keys 32kc+8g..+7
        __builtin_amdgcn_s_setprio(1);
#pragma unroll
        for (int n0 = 0; n0 < 8; n0++) {
          bf16x8 v0 = *(const bf16x8*)(Vl + vcur + kc * 9216 +
                                       ((n0 & 3) * 16 + c) * 144 + (n0 >> 2) * 64 + 16 * g);
          acc[n0] = mfma16(pf, v0, acc[n0]);
        }
        __builtin_amdgcn_s_setprio(0);
      }
    }
    __builtin_amdgcn_s_barrier();
  }

  // epilogue: per-output-row 1/l, exchange U through LDS, combine, write
  float lr0 = __shfl(l, 4 * g), lr1 = __shfl(l, 4 * g + 1);
  float lr2 = __shfl(l, 4 * g + 2), lr3 = __shfl(l, 4 * g + 3);
  f32x4 linv = {1.f / lr0, 1.f / lr1, 1.f / lr2, 1.f / lr3};
  float* Ul = (float*)lds;  // [32][132] overlay = 16.9 KB (all K/V reads done)
  if (!isC) {
#pragma unroll
    for (int n0 = 0; n0 < 8; n0++)
#pragma unroll
      for (int r = 0; r < 4; r++) {
        int urow = 31 - (16 * (w - 2) + 4 * g + r);
        Ul[urow * 132 + n0 * 16 + c] = acc[n0][r] * linv[r];
      }
  }
  __syncthreads();
  if (isC) {
    float alpha = 1.f / (1.f + expf(-alphap[0]));
    float oma = 1.f - alpha;
#pragma unroll
    for (int n0 = 0; n0 < 8; n0++)
#pragma unroll
      for (int r = 0; r < 4; r++) {
        int j = 16 * w + 4 * g + r;
        float uvv = Ul[j * 132 + n0 * 16 + c];
        out[((size_t)b * T_ + q0b + j) * 128 + n0 * 16 + c] =
            alpha * acc[n0][r] * linv[r] + oma * uvv;
      }
  }
}

extern "C" void kernel_launch(void* const* d_in, const int* in_sizes, int n_in,
                              void* d_out, int out_size, void* d_ws, size_t ws_size,
                              hipStream_t stream) {
  const float* x = (const float*)d_in[0];
  const float* Wq = (const float*)d_in[1];
  const float* Wk = (const float*)d_in[2];
  const float* Wv = (const float*)d_in[3];
  const float* falpha = (const float*)d_in[9];
  char* ws = (char*)d_ws;
  float* cosT = (float*)(ws);                  // 1 MB
  float* sinT = (float*)(ws + 1048576);        // 1 MB
  char* WT = ws + 2097152;                     // 768 KB  [384][1024] bf16, pre-swizzled
  short* Qb = (short*)(ws + 2883584);          // 4 MB    roped+scaled Q bf16
  char* Kswz = ws + 7077888;                   // 1 MB    roped pooled K bf16, swizzled
  char* Vswz = ws + 8126464;                   // 1.18 MB pooled V, [b][subtile32][64r][144B]

  prep_kernel<<<2560, 256, 0, stream>>>(Wq, Wk, Wv, cosT, sinT, WT);
  gemm_fused<<<768, 256, 0, stream>>>(x, WT, cosT, sinT, Qb, Kswz, Vswz);
  attn_kernel<<<512, 256, 0, stream>>>(Qb, Kswz, Vswz, falpha, (float*)d_out);
}

// Round 18
// 65.647 us; speedup vs baseline: 1.2926x; 1.2046x over previous
//
#include <hip/hip_runtime.h>
#include <hip/hip_bf16.h>
#include <math.h>

// FluxHead: B=4, T=4096, D_MODEL=1024, HEAD_DIM=128, STRIDE=4, Tk=1024, CAUSAL
// Exact-math simplifications:
//  - spectral gate adds a per-(b,q) scalar to logits -> softmax-invariant -> skipped
//  - reverse branch == unmasked forward attention, output read at mirror row
//  - pooling commutes with K/V projection -> KV blocks pool x DURING A-staging
//    (4x fewer KV MFMA/LDS ops than full-rank-then-pool)
//  - log2e/SCALE folded into Wq -> softmax in exp2 units

#define T_ 4096
#define TK_ 1024

typedef __attribute__((ext_vector_type(8))) short bf16x8;
typedef __attribute__((ext_vector_type(4))) float f32x4;
typedef __attribute__((ext_vector_type(4))) short s16x4;
typedef __attribute__((address_space(1))) unsigned int gas_u32;
typedef __attribute__((address_space(3))) unsigned int las_u32;

__device__ inline short f2bf(float f) {
  unsigned u = __builtin_bit_cast(unsigned, f);
  u = (u + 0x7FFFu + ((u >> 16) & 1u)) >> 16;
  return (short)u;
}
__device__ inline f32x4 mfma16(bf16x8 a, bf16x8 b, f32x4 c) {
  return __builtin_amdgcn_mfma_f32_16x16x32_bf16(a, b, c, 0, 0, 0);
}
__device__ inline void gll16(const void* g, void* l) {
  __builtin_amdgcn_global_load_lds((gas_u32*)g, (las_u32*)l, 16, 0, 0);
}
#define VMCNT(n) asm volatile("s_waitcnt vmcnt(" #n ")" ::: "memory")
#define LGKM0() asm volatile("s_waitcnt lgkmcnt(0)" ::: "memory")

// ---- prep: rope table (blocks 0..1023) + WT pre-swizzle (blocks 1024..2559) ----
__global__ __launch_bounds__(256) void prep_kernel(const float* __restrict__ Wq,
                                                   const float* __restrict__ Wk,
                                                   const float* __restrict__ Wv,
                                                   float* __restrict__ cosT,
                                                   float* __restrict__ sinT,
                                                   char* __restrict__ WT) {
  if (blockIdx.x < 1024) {
    int i = blockIdx.x * 256 + threadIdx.x;  // 262144
    int t = i >> 6, d = i & 63;
    float theta = powf(10000.f, -(float)d * (1.f / 64.f));
    float fr = (float)t * theta;
    cosT[i] = cosf(fr);
    sinT[i] = sinf(fr);
  } else {
    int i = (blockIdx.x - 1024) * 256 + threadIdx.x;  // 384*1024
    int n = i >> 10, k = i & 1023;
    float v;
    if (n < 128) {
      int col = (n >> 6) * 32 + (n & 31) + ((n >> 5) & 1) * 64;
      v = Wq[(size_t)k * 128 + col] * 0.12751741656f;  // log2(e)/sqrt(128)
    } else if (n < 256) {
      int nk = n - 128;
      int col = (nk >> 6) * 32 + (nk & 31) + ((nk >> 5) & 1) * 64;
      v = Wk[(size_t)k * 128 + col];
    } else {
      v = Wv[(size_t)k * 128 + (n - 256)];
    }
    size_t off = (size_t)n * 2048 + (size_t)(k >> 6) * 128 + (((k & 63) * 2) ^ ((n & 7) << 4));
    *(short*)(WT + off) = f2bf(v);
  }
}

// ---- projection GEMM v5: grid 512 = 8 XCD x 32 pairs x {Q, KV}.
// Q kind: byte-identical r15 structure (BM=64, BN=128, nb=0).
// KV kind: pool 64 x-rows -> 16 pooled rows during A-staging; 16x256 tile vs
// [Wk|Wv]; same ring + VMCNT(4) schedule (ALOAD batch = 4 loads both kinds).
__global__ __launch_bounds__(256, 2) void gemm_fused(const float* __restrict__ x,
                                                     const char* __restrict__ WT,
                                                     const float* __restrict__ cosT,
                                                     const float* __restrict__ sinT,
                                                     short* __restrict__ Qb,
                                                     char* __restrict__ Kswz,
                                                     char* __restrict__ Vswz) {
  __shared__ __align__(16) char lds[69632];
  const int tid = threadIdx.x;
  const int w = tid >> 6, g = (tid >> 4) & 3, c = tid & 15;
  const int swc = (c & 7) << 4;
  const int x8 = blockIdx.x & 7, j = blockIdx.x >> 3;  // j: 0..63
  const int kind = j & 1, pr = j >> 1;                 // 32 pairs per XCD
  const int mt = x8 * 32 + pr;                         // 0..255
  const int m0 = mt * 64;

  if (kind == 0) {
    // ================= Q kind (r15-proven body, nb=0) =================
    char* Al[2] = {lds, lds + 8192};
    char* Bl[2] = {lds + 16384, lds + 32768};
    const int wr = w >> 1, wc = w & 1;
    const char* WTB = WT;  // rows 0..127
    const int arow = tid >> 2, apart = tid & 3;
    const int sws = (arow & 7) << 4;
    const float* xsrc = x + (size_t)(m0 + arow) * 1024 + apart * 16;

    f32x4 acc[2][4];
#pragma unroll
    for (int mf = 0; mf < 2; mf++)
#pragma unroll
      for (int n = 0; n < 4; n++) acc[mf][n] = (f32x4){0.f, 0.f, 0.f, 0.f};

    float4 areg[3][4];
    auto ALOAD = [&](int slot, int ki) {
#pragma unroll
      for (int t = 0; t < 4; t++)
        areg[slot][t] = *(const float4*)(xsrc + (size_t)ki * 64 + t * 4);
    };
    auto AWRITE = [&](int buf, int slot) {
      bf16x8 v0 = {f2bf(areg[slot][0].x), f2bf(areg[slot][0].y), f2bf(areg[slot][0].z), f2bf(areg[slot][0].w),
                   f2bf(areg[slot][1].x), f2bf(areg[slot][1].y), f2bf(areg[slot][1].z), f2bf(areg[slot][1].w)};
      bf16x8 v1 = {f2bf(areg[slot][2].x), f2bf(areg[slot][2].y), f2bf(areg[slot][2].z), f2bf(areg[slot][2].w),
                   f2bf(areg[slot][3].x), f2bf(areg[slot][3].y), f2bf(areg[slot][3].z), f2bf(areg[slot][3].w)};
      *(bf16x8*)(Al[buf] + arow * 128 + ((apart * 32) ^ sws)) = v0;
      *(bf16x8*)(Al[buf] + arow * 128 + ((apart * 32 + 16) ^ sws)) = v1;
    };
    auto BSTAGE = [&](int ki, int buf) {
#pragma unroll
      for (int i2 = 0; i2 < 4; i2++) {
        int jj = tid + 256 * i2;
        gll16(WTB + (size_t)(jj >> 3) * 2048 + ki * 128 + (jj & 7) * 16, Bl[buf] + jj * 16);
      }
    };
    auto COMPUTE = [&](int buf) {
#pragma unroll
      for (int kc = 0; kc < 2; kc++) {
        bf16x8 af[2], bfr[4];
#pragma unroll
        for (int mf = 0; mf < 2; mf++)
          af[mf] = *(const bf16x8*)(Al[buf] + (wr * 32 + mf * 16 + c) * 128 + ((kc * 64 + 16 * g) ^ swc));
#pragma unroll
        for (int n0 = 0; n0 < 4; n0++)
          bfr[n0] = *(const bf16x8*)(Bl[buf] + (wc * 64 + n0 * 16 + c) * 128 + ((kc * 64 + 16 * g) ^ swc));
#pragma unroll
        for (int mf = 0; mf < 2; mf++)
#pragma unroll
          for (int n0 = 0; n0 < 4; n0++) acc[mf][n0] = mfma16(af[mf], bfr[n0], acc[mf][n0]);
      }
    };

    ALOAD(0, 0);
    ALOAD(1, 1);
    ALOAD(2, 2);
    AWRITE(0, 0);
    BSTAGE(0, 0);
    VMCNT(0);
    LGKM0();
    __builtin_amdgcn_s_barrier();
#pragma unroll
    for (int ki = 0; ki < 16; ki++) {
      const int cur = ki & 1;
      if (ki + 1 < 16) {
        BSTAGE(ki + 1, cur ^ 1);
        AWRITE(cur ^ 1, (ki + 1) % 3);
        __builtin_amdgcn_sched_barrier(0);
        if (ki + 3 < 16) ALOAD((ki + 3) % 3, ki + 3);
        __builtin_amdgcn_sched_barrier(0);
      }
      COMPUTE(cur);
      if (ki + 3 < 16) { VMCNT(4); } else { VMCNT(0); }
      LGKM0();
      __builtin_amdgcn_s_barrier();
    }

#pragma unroll
    for (int mf = 0; mf < 2; mf++)
#pragma unroll
      for (int r = 0; r < 4; r++) {
        int mm = m0 + wr * 32 + mf * 16 + 4 * g + r;
        int t = mm & 4095;
#pragma unroll
        for (int n0 = 0; n0 < 2; n0++) {
          int d = wc * 32 + n0 * 16 + c;
          float co = cosT[t * 64 + d], si = sinT[t * 64 + d];
          float lo = acc[mf][n0][r], hi = acc[mf][n0 + 2][r];
          Qb[(size_t)mm * 128 + d] = f2bf(lo * co - hi * si);
          Qb[(size_t)mm * 128 + d + 64] = f2bf(hi * co + lo * si);
        }
      }
  } else {
    // ================= KV kind: 16 pooled rows x 256 cols =================
    char* Av[2] = {lds, lds + 2048};
    char* Bv[2] = {lds + 4096, lds + 36864};
    const char* WTB = WT + (size_t)128 * 2048;  // rows 128..383
    const int kp0 = mt * 16;                    // pooled row base
    const int row16 = tid >> 4, p = tid & 15;   // A staging role
    const int sws = (row16 & 7) << 4;
    const float* xsrc = x + (size_t)(m0 + 4 * row16) * 1024 + p * 4;

    f32x4 acc[4];
#pragma unroll
    for (int n = 0; n < 4; n++) acc[n] = (f32x4){0.f, 0.f, 0.f, 0.f};

    float4 areg[3][4];
    auto ALOAD = [&](int slot, int ki) {
#pragma unroll
      for (int rr = 0; rr < 4; rr++)
        areg[slot][rr] = *(const float4*)(xsrc + (size_t)rr * 1024 + ki * 64);
    };
    auto AWRITE = [&](int buf, int slot) {
      float4 a0 = areg[slot][0], a1 = areg[slot][1], a2 = areg[slot][2], a3 = areg[slot][3];
      s16x4 pk = {f2bf(0.25f * (a0.x + a1.x + a2.x + a3.x)),
                  f2bf(0.25f * (a0.y + a1.y + a2.y + a3.y)),
                  f2bf(0.25f * (a0.z + a1.z + a2.z + a3.z)),
                  f2bf(0.25f * (a0.w + a1.w + a2.w + a3.w))};
      *(s16x4*)(Av[buf] + row16 * 128 + ((p * 8) ^ sws)) = pk;
    };
    auto BSTAGE = [&](int ki, int buf) {
#pragma unroll
      for (int i2 = 0; i2 < 8; i2++) {
        int jj = tid + 256 * i2;
        gll16(WTB + (size_t)(jj >> 3) * 2048 + ki * 128 + (jj & 7) * 16, Bv[buf] + jj * 16);
      }
    };
    auto COMPUTE = [&](int buf) {
#pragma unroll
      for (int kc = 0; kc < 2; kc++) {
        bf16x8 af = *(const bf16x8*)(Av[buf] + c * 128 + ((kc * 64 + 16 * g) ^ swc));
        bf16x8 bfr[4];
#pragma unroll
        for (int n0 = 0; n0 < 4; n0++) {
          int row = w * 64 + n0 * 16 + c;
          bfr[n0] = *(const bf16x8*)(Bv[buf] + row * 128 + ((kc * 64 + 16 * g) ^ ((row & 7) << 4)));
        }
#pragma unroll
        for (int n0 = 0; n0 < 4; n0++) acc[n0] = mfma16(af, bfr[n0], acc[n0]);
      }
    };

    ALOAD(0, 0);
    ALOAD(1, 1);
    ALOAD(2, 2);
    AWRITE(0, 0);
    BSTAGE(0, 0);
    VMCNT(0);
    LGKM0();
    __builtin_amdgcn_s_barrier();
#pragma unroll
    for (int ki = 0; ki < 16; ki++) {
      const int cur = ki & 1;
      if (ki + 1 < 16) {
        BSTAGE(ki + 1, cur ^ 1);
        AWRITE(cur ^ 1, (ki + 1) % 3);
        __builtin_amdgcn_sched_barrier(0);
        if (ki + 3 < 16) ALOAD((ki + 3) % 3, ki + 3);
        __builtin_amdgcn_sched_barrier(0);
      }
      COMPUTE(cur);
      if (ki + 3 < 16) { VMCNT(4); } else { VMCNT(0); }
      LGKM0();
      __builtin_amdgcn_s_barrier();
    }

    // epilogue: acc[n0][r] = C[kp0 + 4g + r][kvcol = w*64 + n0*16 + c]
    if (w < 2) {
      // K (reordered cols): lo = acc[n0], hi = acc[n0+2], d = w*32 + n0*16 + c
#pragma unroll
      for (int r = 0; r < 4; r++) {
        int kp = kp0 + 4 * g + r;
        int kpos = kp & 1023;
        int ksw = (kp & 7) << 4;
        char* kb2 = Kswz + (size_t)kp * 256;
#pragma unroll
        for (int n0 = 0; n0 < 2; n0++) {
          int d = w * 32 + n0 * 16 + c;
          float lo = acc[n0][r], hi = acc[n0 + 2][r];
          float co = cosT[kpos * 64 + d], si = sinT[kpos * 64 + d];
          *(short*)(kb2 + ((d * 2) ^ ksw)) = f2bf(lo * co - hi * si);
          *(short*)(kb2 + (((d + 64) * 2) ^ ksw)) = f2bf(hi * co + lo * si);
        }
      }
    } else {
      // V: vcol = (w-2)*64 + n0*16 + c; store [b][subtile32][64 r][144B]
#pragma unroll
      for (int r = 0; r < 4; r++) {
        int kp = kp0 + 4 * g + r;
        int kpos = kp & 1023, bb = kp >> 10;
#pragma unroll
        for (int n0 = 0; n0 < 4; n0++) {
          int vr = n0 * 16 + c;  // row within subtile; h = w-2
          size_t off = (size_t)(bb * 32 + (kpos >> 5)) * 9216 + vr * 144 + (w - 2) * 64 +
                       (kpos & 31) * 2;
          *(short*)(Vswz + off) = f2bf(acc[n0][r]);
        }
      }
    }
  }
}

// ---- fused two-branch flash attention, mirror-paired block, KVBLK=64 ----
// [byte-identical to round-15]
__global__ __launch_bounds__(256, 2) void attn_kernel(const short* __restrict__ Qb,
                                                      const char* __restrict__ Kswz,
                                                      const char* __restrict__ Vswz,
                                                      const float* __restrict__ alphap,
                                                      float* __restrict__ out) {
  __shared__ __align__(16) char lds[32768 + 36864 + 4 * 2304];  // K + V + P = 78848
  char* Kl = lds;            // 2 bufs x [64 keys x 256B] (pre-swz rows)
  char* Vl = lds + 32768;    // 2 bufs x [2 subtiles x [64 r][144B]]
  const int tid = threadIdx.x;
  const int w = tid >> 6, g = (tid >> 4) & 3, c = tid & 15;
  char* Pl = lds + 69632 + w * 2304;  // 16 q-rows x 144B
  const int blk = blockIdx.x;
  const int b = blk >> 7, qc = blk & 127;
  const int q0b = qc * 32;
  const bool isC = (w < 2);
  const int qbase = isC ? (q0b + w * 16) : (4064 - q0b + (w - 2) * 16);
  const int myq = qbase + c;
  const int tile_b = qbase >> 8;  // boundary 64-key tile for this wave
  const int swc = (c & 7) << 4;

  bf16x8 qf[4];
  {
    const short* qr = Qb + ((size_t)b * T_ + myq) * 128;
#pragma unroll
    for (int kc = 0; kc < 4; kc++) qf[kc] = *(const bf16x8*)(qr + kc * 32 + 8 * g);
  }
  f32x4 acc[8];
#pragma unroll
  for (int n = 0; n < 8; n++) acc[n] = (f32x4){0.f, 0.f, 0.f, 0.f};
  float m = -1e30f, l = 0.f;

  const char* kbB = Kswz + (size_t)b * 262144;
  const char* vbB = Vswz + (size_t)b * 294912;

  auto STG = [&](int tg, char* kd, char* vd) {
    const char* kb = kbB + (size_t)tg * 16384;
    const char* vb = vbB + (size_t)tg * 18432;
#pragma unroll
    for (int jj = 0; jj < 4; jj++) gll16(kb + jj * 4096 + tid * 16, kd + jj * 4096 + tid * 16);
#pragma unroll
    for (int jj = 0; jj < 4; jj++) gll16(vb + jj * 4096 + tid * 16, vd + jj * 4096 + tid * 16);
    if (tid < 128) gll16(vb + 16384 + tid * 16, vd + 16384 + tid * 16);  // 2KB tail
  };

  STG(0, Kl, Vl);

#pragma unroll 1
  for (int tg = 0; tg < 16; tg++) {
    const int kcur = (tg & 1) * 16384;
    const int vcur = (tg & 1) * 18432;
    if (tg < 15) {
      STG(tg + 1, Kl + (16384 - kcur), Vl + (18432 - vcur));
      if (w < 2) { VMCNT(9); } else { VMCNT(8); }  // drain prev tile; keep newest
    } else {
      VMCNT(0);
    }
    __builtin_amdgcn_s_barrier();

    if (!isC || tg <= tile_b) {
      // QK^T swapped: s[n][r] = S[key = tg*64 + 16n + 4g + r][q = myq]
      f32x4 s[4];
#pragma unroll
      for (int n = 0; n < 4; n++) s[n] = (f32x4){0.f, 0.f, 0.f, 0.f};
      __builtin_amdgcn_s_setprio(1);
#pragma unroll
      for (int kc = 0; kc < 4; kc++) {
#pragma unroll
        for (int n = 0; n < 4; n++) {
          bf16x8 kf = *(const bf16x8*)(Kl + kcur + (16 * n + c) * 256 + ((kc * 64 + 16 * g) ^ swc));
          s[n] = mfma16(kf, qf[kc], s[n]);
        }
      }
      __builtin_amdgcn_s_setprio(0);
      if (isC && tg == tile_b) {  // boundary mask
        int klim = (myq >> 2) - tg * 64;
#pragma unroll
        for (int n = 0; n < 4; n++)
#pragma unroll
          for (int r = 0; r < 4; r++)
            if (16 * n + 4 * g + r > klim) s[n][r] = -3.0e38f;
      }
      float tm = fmaxf(fmaxf(fmaxf(s[0][0], s[0][1]), fmaxf(s[0][2], s[0][3])),
                       fmaxf(fmaxf(s[1][0], s[1][1]), fmaxf(s[1][2], s[1][3])));
      tm = fmaxf(tm, fmaxf(fmaxf(fmaxf(s[2][0], s[2][1]), fmaxf(s[2][2], s[2][3])),
                           fmaxf(fmaxf(s[3][0], s[3][1]), fmaxf(s[3][2], s[3][3]))));
      tm = fmaxf(tm, __shfl_xor(tm, 16));
      tm = fmaxf(tm, __shfl_xor(tm, 32));
      if (__any(tm > m + 8.f)) {  // defer-max
        float mn = fmaxf(m, tm);
        float sc = __builtin_amdgcn_exp2f(m - mn);
        m = mn;
        l *= sc;
        float s0 = __shfl(sc, 4 * g), s1 = __shfl(sc, 4 * g + 1);
        float s2 = __shfl(sc, 4 * g + 2), s3 = __shfl(sc, 4 * g + 3);
        f32x4 scv = {s0, s1, s2, s3};
#pragma unroll
        for (int n0 = 0; n0 < 8; n0++) acc[n0] *= scv;
      }
      float rsum = 0.f;
#pragma unroll
      for (int n = 0; n < 4; n++) {
        float p0 = __builtin_amdgcn_exp2f(s[n][0] - m);
        float p1 = __builtin_amdgcn_exp2f(s[n][1] - m);
        float p2 = __builtin_amdgcn_exp2f(s[n][2] - m);
        float p3 = __builtin_amdgcn_exp2f(s[n][3] - m);
        rsum += (p0 + p1) + (p2 + p3);
        s16x4 pk = {f2bf(p0), f2bf(p1), f2bf(p2), f2bf(p3)};
        *(s16x4*)(Pl + c * 144 + 32 * n + 8 * g) = pk;  // keys 16n+4g..+3
      }
      rsum += __shfl_xor(rsum, 16);
      rsum += __shfl_xor(rsum, 32);
      l += rsum;
#pragma unroll
      for (int kc = 0; kc < 2; kc++) {
        bf16x8 pf = *(const bf16x8*)(Pl + c * 144 + 64 * kc + 16 * g);  // keys 32kc+8g..+7
        __builtin_amdgcn_s_setprio(1);
#pragma unroll
        for (int n0 = 0; n0 < 8; n0++) {
          bf16x8 v0 = *(const bf16x8*)(Vl + vcur + kc * 9216 +
                                       ((n0 & 3) * 16 + c) * 144 + (n0 >> 2) * 64 + 16 * g);
          acc[n0] = mfma16(pf, v0, acc[n0]);
        }
        __builtin_amdgcn_s_setprio(0);
      }
    }
    __builtin_amdgcn_s_barrier();
  }

  // epilogue: per-output-row 1/l, exchange U through LDS, combine, write
  float lr0 = __shfl(l, 4 * g), lr1 = __shfl(l, 4 * g + 1);
  float lr2 = __shfl(l, 4 * g + 2), lr3 = __shfl(l, 4 * g + 3);
  f32x4 linv = {1.f / lr0, 1.f / lr1, 1.f / lr2, 1.f / lr3};
  float* Ul = (float*)lds;  // [32][132] overlay = 16.9 KB (all K/V reads done)
  if (!isC) {
#pragma unroll
    for (int n0 = 0; n0 < 8; n0++)
#pragma unroll
      for (int r = 0; r < 4; r++) {
        int urow = 31 - (16 * (w - 2) + 4 * g + r);
        Ul[urow * 132 + n0 * 16 + c] = acc[n0][r] * linv[r];
      }
  }
  __syncthreads();
  if (isC) {
    float alpha = 1.f / (1.f + expf(-alphap[0]));
    float oma = 1.f - alpha;
#pragma unroll
    for (int n0 = 0; n0 < 8; n0++)
#pragma unroll
      for (int r = 0; r < 4; r++) {
        int j2 = 16 * w + 4 * g + r;
        float uvv = Ul[j2 * 132 + n0 * 16 + c];
        out[((size_t)b * T_ + q0b + j2) * 128 + n0 * 16 + c] =
            alpha * acc[n0][r] * linv[r] + oma * uvv;
      }
  }
}

extern "C" void kernel_launch(void* const* d_in, const int* in_sizes, int n_in,
                              void* d_out, int out_size, void* d_ws, size_t ws_size,
                              hipStream_t stream) {
  const float* x = (const float*)d_in[0];
  const float* Wq = (const float*)d_in[1];
  const float* Wk = (const float*)d_in[2];
  const float* Wv = (const float*)d_in[3];
  const float* falpha = (const float*)d_in[9];
  char* ws = (char*)d_ws;
  float* cosT = (float*)(ws);                  // 1 MB
  float* sinT = (float*)(ws + 1048576);        // 1 MB
  char* WT = ws + 2097152;                     // 768 KB  [384][1024] bf16, pre-swizzled
  short* Qb = (short*)(ws + 2883584);          // 4 MB    roped+scaled Q bf16
  char* Kswz = ws + 7077888;                   // 1 MB    roped pooled K bf16, swizzled
  char* Vswz = ws + 8126464;                   // 1.18 MB pooled V, [b][subtile32][64r][144B]

  prep_kernel<<<2560, 256, 0, stream>>>(Wq, Wk, Wv, cosT, sinT, WT);
  gemm_fused<<<512, 256, 0, stream>>>(x, WT, cosT, sinT, Qb, Kswz, Vswz);
  attn_kernel<<<512, 256, 0, stream>>>(Qb, Kswz, Vswz, falpha, (float*)d_out);
}

// Round 19
// 63.763 us; speedup vs baseline: 1.3308x; 1.0296x over previous
//
#include <hip/hip_runtime.h>
#include <hip/hip_bf16.h>
#include <math.h>

// FluxHead: B=4, T=4096, D_MODEL=1024, HEAD_DIM=128, STRIDE=4, Tk=1024, CAUSAL
// Exact-math simplifications:
//  - spectral gate adds a per-(b,q) scalar to logits -> softmax-invariant -> skipped
//  - reverse branch == unmasked forward attention, output read at mirror row
//  - pooling commutes with K/V projection -> KV blocks pool x DURING A-staging
//  - log2e/SCALE folded into Wq -> softmax in exp2 units

#define T_ 4096
#define TK_ 1024

typedef __attribute__((ext_vector_type(8))) short bf16x8;
typedef __attribute__((ext_vector_type(4))) float f32x4;
typedef __attribute__((ext_vector_type(4))) short s16x4;
typedef __attribute__((address_space(1))) unsigned int gas_u32;
typedef __attribute__((address_space(3))) unsigned int las_u32;

__device__ inline short f2bf(float f) {
  unsigned u = __builtin_bit_cast(unsigned, f);
  u = (u + 0x7FFFu + ((u >> 16) & 1u)) >> 16;
  return (short)u;
}
__device__ inline f32x4 mfma16(bf16x8 a, bf16x8 b, f32x4 c) {
  return __builtin_amdgcn_mfma_f32_16x16x32_bf16(a, b, c, 0, 0, 0);
}
__device__ inline void gll16(const void* g, void* l) {
  __builtin_amdgcn_global_load_lds((gas_u32*)g, (las_u32*)l, 16, 0, 0);
}
#define VMCNT(n) asm volatile("s_waitcnt vmcnt(" #n ")" ::: "memory")
#define LGKM0() asm volatile("s_waitcnt lgkmcnt(0)" ::: "memory")

// ---- prep: rope table (blocks 0..1023) + WT pre-swizzle (blocks 1024..2559) ----
__global__ __launch_bounds__(256) void prep_kernel(const float* __restrict__ Wq,
                                                   const float* __restrict__ Wk,
                                                   const float* __restrict__ Wv,
                                                   float* __restrict__ cosT,
                                                   float* __restrict__ sinT,
                                                   char* __restrict__ WT) {
  if (blockIdx.x < 1024) {
    int i = blockIdx.x * 256 + threadIdx.x;  // 262144
    int t = i >> 6, d = i & 63;
    float theta = powf(10000.f, -(float)d * (1.f / 64.f));
    float fr = (float)t * theta;
    cosT[i] = cosf(fr);
    sinT[i] = sinf(fr);
  } else {
    int i = (blockIdx.x - 1024) * 256 + threadIdx.x;  // 384*1024
    int n = i >> 10, k = i & 1023;
    float v;
    if (n < 128) {
      int col = (n >> 6) * 32 + (n & 31) + ((n >> 5) & 1) * 64;
      v = Wq[(size_t)k * 128 + col] * 0.12751741656f;  // log2(e)/sqrt(128)
    } else if (n < 256) {
      int nk = n - 128;
      int col = (nk >> 6) * 32 + (nk & 31) + ((nk >> 5) & 1) * 64;
      v = Wk[(size_t)k * 128 + col];
    } else {
      v = Wv[(size_t)k * 128 + (n - 256)];
    }
    size_t off = (size_t)n * 2048 + (size_t)(k >> 6) * 128 + (((k & 63) * 2) ^ ((n & 7) << 4));
    *(short*)(WT + off) = f2bf(v);
  }
}

// ---- projection GEMM v5 (byte-identical to round 18) ----
__global__ __launch_bounds__(256, 2) void gemm_fused(const float* __restrict__ x,
                                                     const char* __restrict__ WT,
                                                     const float* __restrict__ cosT,
                                                     const float* __restrict__ sinT,
                                                     short* __restrict__ Qb,
                                                     char* __restrict__ Kswz,
                                                     char* __restrict__ Vswz) {
  __shared__ __align__(16) char lds[69632];
  const int tid = threadIdx.x;
  const int w = tid >> 6, g = (tid >> 4) & 3, c = tid & 15;
  const int swc = (c & 7) << 4;
  const int x8 = blockIdx.x & 7, j = blockIdx.x >> 3;  // j: 0..63
  const int kind = j & 1, pr = j >> 1;                 // 32 pairs per XCD
  const int mt = x8 * 32 + pr;                         // 0..255
  const int m0 = mt * 64;

  if (kind == 0) {
    char* Al[2] = {lds, lds + 8192};
    char* Bl[2] = {lds + 16384, lds + 32768};
    const int wr = w >> 1, wc = w & 1;
    const char* WTB = WT;  // rows 0..127
    const int arow = tid >> 2, apart = tid & 3;
    const int sws = (arow & 7) << 4;
    const float* xsrc = x + (size_t)(m0 + arow) * 1024 + apart * 16;

    f32x4 acc[2][4];
#pragma unroll
    for (int mf = 0; mf < 2; mf++)
#pragma unroll
      for (int n = 0; n < 4; n++) acc[mf][n] = (f32x4){0.f, 0.f, 0.f, 0.f};

    float4 areg[3][4];
    auto ALOAD = [&](int slot, int ki) {
#pragma unroll
      for (int t = 0; t < 4; t++)
        areg[slot][t] = *(const float4*)(xsrc + (size_t)ki * 64 + t * 4);
    };
    auto AWRITE = [&](int buf, int slot) {
      bf16x8 v0 = {f2bf(areg[slot][0].x), f2bf(areg[slot][0].y), f2bf(areg[slot][0].z), f2bf(areg[slot][0].w),
                   f2bf(areg[slot][1].x), f2bf(areg[slot][1].y), f2bf(areg[slot][1].z), f2bf(areg[slot][1].w)};
      bf16x8 v1 = {f2bf(areg[slot][2].x), f2bf(areg[slot][2].y), f2bf(areg[slot][2].z), f2bf(areg[slot][2].w),
                   f2bf(areg[slot][3].x), f2bf(areg[slot][3].y), f2bf(areg[slot][3].z), f2bf(areg[slot][3].w)};
      *(bf16x8*)(Al[buf] + arow * 128 + ((apart * 32) ^ sws)) = v0;
      *(bf16x8*)(Al[buf] + arow * 128 + ((apart * 32 + 16) ^ sws)) = v1;
    };
    auto BSTAGE = [&](int ki, int buf) {
#pragma unroll
      for (int i2 = 0; i2 < 4; i2++) {
        int jj = tid + 256 * i2;
        gll16(WTB + (size_t)(jj >> 3) * 2048 + ki * 128 + (jj & 7) * 16, Bl[buf] + jj * 16);
      }
    };
    auto COMPUTE = [&](int buf) {
#pragma unroll
      for (int kc = 0; kc < 2; kc++) {
        bf16x8 af[2], bfr[4];
#pragma unroll
        for (int mf = 0; mf < 2; mf++)
          af[mf] = *(const bf16x8*)(Al[buf] + (wr * 32 + mf * 16 + c) * 128 + ((kc * 64 + 16 * g) ^ swc));
#pragma unroll
        for (int n0 = 0; n0 < 4; n0++)
          bfr[n0] = *(const bf16x8*)(Bl[buf] + (wc * 64 + n0 * 16 + c) * 128 + ((kc * 64 + 16 * g) ^ swc));
#pragma unroll
        for (int mf = 0; mf < 2; mf++)
#pragma unroll
          for (int n0 = 0; n0 < 4; n0++) acc[mf][n0] = mfma16(af[mf], bfr[n0], acc[mf][n0]);
      }
    };

    ALOAD(0, 0);
    ALOAD(1, 1);
    ALOAD(2, 2);
    AWRITE(0, 0);
    BSTAGE(0, 0);
    VMCNT(0);
    LGKM0();
    __builtin_amdgcn_s_barrier();
#pragma unroll
    for (int ki = 0; ki < 16; ki++) {
      const int cur = ki & 1;
      if (ki + 1 < 16) {
        BSTAGE(ki + 1, cur ^ 1);
        AWRITE(cur ^ 1, (ki + 1) % 3);
        __builtin_amdgcn_sched_barrier(0);
        if (ki + 3 < 16) ALOAD((ki + 3) % 3, ki + 3);
        __builtin_amdgcn_sched_barrier(0);
      }
      COMPUTE(cur);
      if (ki + 3 < 16) { VMCNT(4); } else { VMCNT(0); }
      LGKM0();
      __builtin_amdgcn_s_barrier();
    }

#pragma unroll
    for (int mf = 0; mf < 2; mf++)
#pragma unroll
      for (int r = 0; r < 4; r++) {
        int mm = m0 + wr * 32 + mf * 16 + 4 * g + r;
        int t = mm & 4095;
#pragma unroll
        for (int n0 = 0; n0 < 2; n0++) {
          int d = wc * 32 + n0 * 16 + c;
          float co = cosT[t * 64 + d], si = sinT[t * 64 + d];
          float lo = acc[mf][n0][r], hi = acc[mf][n0 + 2][r];
          Qb[(size_t)mm * 128 + d] = f2bf(lo * co - hi * si);
          Qb[(size_t)mm * 128 + d + 64] = f2bf(hi * co + lo * si);
        }
      }
  } else {
    char* Av[2] = {lds, lds + 2048};
    char* Bv[2] = {lds + 4096, lds + 36864};
    const char* WTB = WT + (size_t)128 * 2048;  // rows 128..383
    const int kp0 = mt * 16;
    const int row16 = tid >> 4, p = tid & 15;
    const int sws = (row16 & 7) << 4;
    const float* xsrc = x + (size_t)(m0 + 4 * row16) * 1024 + p * 4;

    f32x4 acc[4];
#pragma unroll
    for (int n = 0; n < 4; n++) acc[n] = (f32x4){0.f, 0.f, 0.f, 0.f};

    float4 areg[3][4];
    auto ALOAD = [&](int slot, int ki) {
#pragma unroll
      for (int rr = 0; rr < 4; rr++)
        areg[slot][rr] = *(const float4*)(xsrc + (size_t)rr * 1024 + ki * 64);
    };
    auto AWRITE = [&](int buf, int slot) {
      float4 a0 = areg[slot][0], a1 = areg[slot][1], a2 = areg[slot][2], a3 = areg[slot][3];
      s16x4 pk = {f2bf(0.25f * (a0.x + a1.x + a2.x + a3.x)),
                  f2bf(0.25f * (a0.y + a1.y + a2.y + a3.y)),
                  f2bf(0.25f * (a0.z + a1.z + a2.z + a3.z)),
                  f2bf(0.25f * (a0.w + a1.w + a2.w + a3.w))};
      *(s16x4*)(Av[buf] + row16 * 128 + ((p * 8) ^ sws)) = pk;
    };
    auto BSTAGE = [&](int ki, int buf) {
#pragma unroll
      for (int i2 = 0; i2 < 8; i2++) {
        int jj = tid + 256 * i2;
        gll16(WTB + (size_t)(jj >> 3) * 2048 + ki * 128 + (jj & 7) * 16, Bv[buf] + jj * 16);
      }
    };
    auto COMPUTE = [&](int buf) {
#pragma unroll
      for (int kc = 0; kc < 2; kc++) {
        bf16x8 af = *(const bf16x8*)(Av[buf] + c * 128 + ((kc * 64 + 16 * g) ^ swc));
        bf16x8 bfr[4];
#pragma unroll
        for (int n0 = 0; n0 < 4; n0++) {
          int row = w * 64 + n0 * 16 + c;
          bfr[n0] = *(const bf16x8*)(Bv[buf] + row * 128 + ((kc * 64 + 16 * g) ^ ((row & 7) << 4)));
        }
#pragma unroll
        for (int n0 = 0; n0 < 4; n0++) acc[n0] = mfma16(af, bfr[n0], acc[n0]);
      }
    };

    ALOAD(0, 0);
    ALOAD(1, 1);
    ALOAD(2, 2);
    AWRITE(0, 0);
    BSTAGE(0, 0);
    VMCNT(0);
    LGKM0();
    __builtin_amdgcn_s_barrier();
#pragma unroll
    for (int ki = 0; ki < 16; ki++) {
      const int cur = ki & 1;
      if (ki + 1 < 16) {
        BSTAGE(ki + 1, cur ^ 1);
        AWRITE(cur ^ 1, (ki + 1) % 3);
        __builtin_amdgcn_sched_barrier(0);
        if (ki + 3 < 16) ALOAD((ki + 3) % 3, ki + 3);
        __builtin_amdgcn_sched_barrier(0);
      }
      COMPUTE(cur);
      if (ki + 3 < 16) { VMCNT(4); } else { VMCNT(0); }
      LGKM0();
      __builtin_amdgcn_s_barrier();
    }

    if (w < 2) {
#pragma unroll
      for (int r = 0; r < 4; r++) {
        int kp = kp0 + 4 * g + r;
        int kpos = kp & 1023;
        int ksw = (kp & 7) << 4;
        char* kb2 = Kswz + (size_t)kp * 256;
#pragma unroll
        for (int n0 = 0; n0 < 2; n0++) {
          int d = w * 32 + n0 * 16 + c;
          float lo = acc[n0][r], hi = acc[n0 + 2][r];
          float co = cosT[kpos * 64 + d], si = sinT[kpos * 64 + d];
          *(short*)(kb2 + ((d * 2) ^ ksw)) = f2bf(lo * co - hi * si);
          *(short*)(kb2 + (((d + 64) * 2) ^ ksw)) = f2bf(hi * co + lo * si);
        }
      }
    } else {
#pragma unroll
      for (int r = 0; r < 4; r++) {
        int kp = kp0 + 4 * g + r;
        int kpos = kp & 1023, bb = kp >> 10;
#pragma unroll
        for (int n0 = 0; n0 < 4; n0++) {
          int vr = n0 * 16 + c;
          size_t off = (size_t)(bb * 32 + (kpos >> 5)) * 9216 + vr * 144 + (w - 2) * 64 +
                       (kpos & 31) * 2;
          *(short*)(Vswz + off) = f2bf(acc[n0][r]);
        }
      }
    }
  }
}

// ---- fused two-branch flash attention, 8-wave merged block, KVBLK=64 ----
// grid 256, 512 thr = 8 waves: w0-3 causal rows [q0b, q0b+64); w4-7 unmasked
// mirror rows [4032-q0b, 4096-q0b). Each K/V byte staged once serves 2x q rows
// (staging instrs halved vs r15's 2 paired blocks). Per-wave body identical.
__global__ __launch_bounds__(512, 1) void attn_kernel(const short* __restrict__ Qb,
                                                      const char* __restrict__ Kswz,
                                                      const char* __restrict__ Vswz,
                                                      const float* __restrict__ alphap,
                                                      float* __restrict__ out) {
  __shared__ __align__(16) char lds[32768 + 36864 + 8 * 2304];  // K + V + P = 88064
  char* Kl = lds;            // 2 bufs x [64 keys x 256B] (pre-swz rows)
  char* Vl = lds + 32768;    // 2 bufs x [2 subtiles x [64 r][144B]]
  const int tid = threadIdx.x;
  const int w = tid >> 6, g = (tid >> 4) & 3, c = tid & 15;
  char* Pl = lds + 69632 + w * 2304;  // 16 q-rows x 144B per wave
  const int blk = blockIdx.x;
  const int b = blk >> 6, qc = blk & 63;
  const int q0b = qc * 64;
  const bool isC = (w < 4);
  const int qbase = isC ? (q0b + w * 16) : (4032 - q0b + (w - 4) * 16);
  const int myq = qbase + c;
  const int tile_b = qbase >> 8;  // boundary 64-key tile for this wave
  const int swc = (c & 7) << 4;

  bf16x8 qf[4];
  {
    const short* qr = Qb + ((size_t)b * T_ + myq) * 128;
#pragma unroll
    for (int kc = 0; kc < 4; kc++) qf[kc] = *(const bf16x8*)(qr + kc * 32 + 8 * g);
  }
  f32x4 acc[8];
#pragma unroll
  for (int n = 0; n < 8; n++) acc[n] = (f32x4){0.f, 0.f, 0.f, 0.f};
  float m = -1e30f, l = 0.f;

  const char* kbB = Kswz + (size_t)b * 262144;
  const char* vbB = Vswz + (size_t)b * 294912;

  // stage one 64-key tile with 512 threads: K 2 chunks/thr, V 2 + tail (tid<128)
  auto STG = [&](int tg, char* kd, char* vd) {
    const char* kb = kbB + (size_t)tg * 16384;
    const char* vb = vbB + (size_t)tg * 18432;
#pragma unroll
    for (int jj = 0; jj < 2; jj++) gll16(kb + jj * 8192 + tid * 16, kd + jj * 8192 + tid * 16);
#pragma unroll
    for (int jj = 0; jj < 2; jj++) gll16(vb + jj * 8192 + tid * 16, vd + jj * 8192 + tid * 16);
    if (tid < 128) gll16(vb + 16384 + tid * 16, vd + 16384 + tid * 16);  // 2KB tail
  };

  STG(0, Kl, Vl);

#pragma unroll 1
  for (int tg = 0; tg < 16; tg++) {
    const int kcur = (tg & 1) * 16384;
    const int vcur = (tg & 1) * 18432;
    if (tg < 15) {
      STG(tg + 1, Kl + (16384 - kcur), Vl + (18432 - vcur));
      if (w < 2) { VMCNT(5); } else { VMCNT(4); }  // drain prev tile; keep newest
    } else {
      VMCNT(0);
    }
    __builtin_amdgcn_s_barrier();

    if (!isC || tg <= tile_b) {
      // QK^T swapped: s[n][r] = S[key = tg*64 + 16n + 4g + r][q = myq]
      f32x4 s[4];
#pragma unroll
      for (int n = 0; n < 4; n++) s[n] = (f32x4){0.f, 0.f, 0.f, 0.f};
      __builtin_amdgcn_s_setprio(1);
#pragma unroll
      for (int kc = 0; kc < 4; kc++) {
#pragma unroll
        for (int n = 0; n < 4; n++) {
          bf16x8 kf = *(const bf16x8*)(Kl + kcur + (16 * n + c) * 256 + ((kc * 64 + 16 * g) ^ swc));
          s[n] = mfma16(kf, qf[kc], s[n]);
        }
      }
      __builtin_amdgcn_s_setprio(0);
      if (isC && tg == tile_b) {  // boundary mask
        int klim = (myq >> 2) - tg * 64;
#pragma unroll
        for (int n = 0; n < 4; n++)
#pragma unroll
          for (int r = 0; r < 4; r++)
            if (16 * n + 4 * g + r > klim) s[n][r] = -3.0e38f;
      }
      float tm = fmaxf(fmaxf(fmaxf(s[0][0], s[0][1]), fmaxf(s[0][2], s[0][3])),
                       fmaxf(fmaxf(s[1][0], s[1][1]), fmaxf(s[1][2], s[1][3])));
      tm = fmaxf(tm, fmaxf(fmaxf(fmaxf(s[2][0], s[2][1]), fmaxf(s[2][2], s[2][3])),
                           fmaxf(fmaxf(s[3][0], s[3][1]), fmaxf(s[3][2], s[3][3]))));
      tm = fmaxf(tm, __shfl_xor(tm, 16));
      tm = fmaxf(tm, __shfl_xor(tm, 32));
      if (__any(tm > m + 8.f)) {  // defer-max
        float mn = fmaxf(m, tm);
        float sc = __builtin_amdgcn_exp2f(m - mn);
        m = mn;
        l *= sc;
        float s0 = __shfl(sc, 4 * g), s1 = __shfl(sc, 4 * g + 1);
        float s2 = __shfl(sc, 4 * g + 2), s3 = __shfl(sc, 4 * g + 3);
        f32x4 scv = {s0, s1, s2, s3};
#pragma unroll
        for (int n0 = 0; n0 < 8; n0++) acc[n0] *= scv;
      }
      float rsum = 0.f;
#pragma unroll
      for (int n = 0; n < 4; n++) {
        float p0 = __builtin_amdgcn_exp2f(s[n][0] - m);
        float p1 = __builtin_amdgcn_exp2f(s[n][1] - m);
        float p2 = __builtin_amdgcn_exp2f(s[n][2] - m);
        float p3 = __builtin_amdgcn_exp2f(s[n][3] - m);
        rsum += (p0 + p1) + (p2 + p3);
        s16x4 pk = {f2bf(p0), f2bf(p1), f2bf(p2), f2bf(p3)};
        *(s16x4*)(Pl + c * 144 + 32 * n + 8 * g) = pk;  // keys 16n+4g..+3
      }
      rsum += __shfl_xor(rsum, 16);
      rsum += __shfl_xor(rsum, 32);
      l += rsum;
#pragma unroll
      for (int kc = 0; kc < 2; kc++) {
        bf16x8 pf = *(const bf16x8*)(Pl + c * 144 + 64 * kc + 16 * g);  // keys 32kc+8g..+7
        __builtin_amdgcn_s_setprio(1);
#pragma unroll
        for (int n0 = 0; n0 < 8; n0++) {
          bf16x8 v0 = *(const bf16x8*)(Vl + vcur + kc * 9216 +
                                       ((n0 & 3) * 16 + c) * 144 + (n0 >> 2) * 64 + 16 * g);
          acc[n0] = mfma16(pf, v0, acc[n0]);
        }
        __builtin_amdgcn_s_setprio(0);
      }
    }
    __builtin_amdgcn_s_barrier();
  }

  // epilogue: per-output-row 1/l, exchange U through LDS, combine, write
  float lr0 = __shfl(l, 4 * g), lr1 = __shfl(l, 4 * g + 1);
  float lr2 = __shfl(l, 4 * g + 2), lr3 = __shfl(l, 4 * g + 3);
  f32x4 linv = {1.f / lr0, 1.f / lr1, 1.f / lr2, 1.f / lr3};
  float* Ul = (float*)lds;  // [64][132] overlay = 33.8 KB (all K/V reads done)
  if (!isC) {
#pragma unroll
    for (int n0 = 0; n0 < 8; n0++)
#pragma unroll
      for (int r = 0; r < 4; r++) {
        int v = 16 * (w - 4) + 4 * g + r;          // local mirror row
        Ul[(63 - v) * 132 + n0 * 16 + c] = acc[n0][r] * linv[r];
      }
  }
  __syncthreads();
  if (isC) {
    float alpha = 1.f / (1.f + expf(-alphap[0]));
    float oma = 1.f - alpha;
#pragma unroll
    for (int n0 = 0; n0 < 8; n0++)
#pragma unroll
      for (int r = 0; r < 4; r++) {
        int j2 = 16 * w + 4 * g + r;
        float uvv = Ul[j2 * 132 + n0 * 16 + c];
        out[((size_t)b * T_ + q0b + j2) * 128 + n0 * 16 + c] =
            alpha * acc[n0][r] * linv[r] + oma * uvv;
      }
  }
}

extern "C" void kernel_launch(void* const* d_in, const int* in_sizes, int n_in,
                              void* d_out, int out_size, void* d_ws, size_t ws_size,
                              hipStream_t stream) {
  const float* x = (const float*)d_in[0];
  const float* Wq = (const float*)d_in[1];
  const float* Wk = (const float*)d_in[2];
  const float* Wv = (const float*)d_in[3];
  const float* falpha = (const float*)d_in[9];
  char* ws = (char*)d_ws;
  float* cosT = (float*)(ws);                  // 1 MB
  float* sinT = (float*)(ws + 1048576);        // 1 MB
  char* WT = ws + 2097152;                     // 768 KB  [384][1024] bf16, pre-swizzled
  short* Qb = (short*)(ws + 2883584);          // 4 MB    roped+scaled Q bf16
  char* Kswz = ws + 7077888;                   // 1 MB    roped pooled K bf16, swizzled
  char* Vswz = ws + 8126464;                   // 1.18 MB pooled V, [b][subtile32][64r][144B]

  prep_kernel<<<2560, 256, 0, stream>>>(Wq, Wk, Wv, cosT, sinT, WT);
  gemm_fused<<<512, 256, 0, stream>>>(x, WT, cosT, sinT, Qb, Kswz, Vswz);
  attn_kernel<<<256, 512, 0, stream>>>(Qb, Kswz, Vswz, falpha, (float*)d_out);
}